// Round 18
// baseline (217.425 us; speedup 1.0000x reference)
//
#include <hip/hip_runtime.h>
#include <hip/hip_bf16.h>
#include <cstdint>
#include <cstddef>

#define NPTS 16000
#define KNB  16
#define CDIM 384
#define NH   6
#define HDIM 64
#define T2C  49
#define NL3T 147             // 49*3 table rows
#define THR  160             // per-head table rows padded (147 used)
#define NXC  1152            // q|k|v GEMM output cols
#define KVROW 256            // kvh row bytes: k bf16 [0,128) | v bf16 [128,256)
// head-major buffers:
//   qh [h][n][128B bf16]   kvh[h][n][256B] (k|v bf16)
//   dqh[h][n][160B fp8x8]  (dk is recomputed as k.Tksum in attn — no dkh)
//   Tvh f32 [h][160][64] (L2-hot)   Tkh bf16 [h][160][64] (20KB/head, L1-hot)

static constexpr float WIN    = 6.0f;
static constexpr float QUANT  = 0.24f;
static constexpr float QSCALE = 0.125f; // 64^-0.5
static constexpr float DQS    = 8.0f;   // fp8 range pre-scale for dq
static constexpr float DQSINV = 0.125f;

typedef __attribute__((ext_vector_type(8))) short short8;
typedef __attribute__((ext_vector_type(4))) float floatx4;
typedef __attribute__((ext_vector_type(4))) unsigned short ushort4v;
typedef __attribute__((ext_vector_type(2))) float float2v;

__device__ inline unsigned short f2bf(float x) {
    unsigned int u = __float_as_uint(x);
    unsigned int r = (u + 0x7fffu + ((u >> 16) & 1u)) >> 16;
    return (unsigned short)r;
}
__device__ inline float bf2f(unsigned short b) {
    return __uint_as_float(((unsigned int)b) << 16);
}
__device__ inline float f8tof(unsigned char b) {
    return __builtin_amdgcn_cvt_f32_fp8((int)b, 0);
}
// unpack a bf16x2 word into {elem0, elem1} as f32 (2 VALU ops)
__device__ inline float2v bfpair(unsigned int w) {
    float2v r;
    r.x = __uint_as_float(w << 16);
    r.y = __uint_as_float(w & 0xffff0000u);
    return r;
}

// bijective XCD-chunked (m204) decode for grid (NPTS/4, NH)
__device__ inline void swz_nh(int& nb, int& h) {
    const int gx   = gridDim.x;
    const int nwg  = gx * NH;
    const int orig = blockIdx.y * gx + blockIdx.x;
    const int q    = nwg >> 3, r = nwg & 7;
    const int xcd  = orig & 7, idx = orig >> 3;
    const int wg   = (xcd < r ? xcd * (q + 1) : r * (q + 1) + (xcd - r) * q) + idx;
    h  = wg / gx;
    nb = wg % gx;
}

// ---------------------------------------------------------------- min reduce
// minbits pre-set to 0x7f7f7f7f (≈3.4e38) via hipMemsetAsync
__global__ void min_kernel(const float* __restrict__ xyz,
                           unsigned int* __restrict__ minbits) {
    float m0 = INFINITY, m1 = INFINITY, m2 = INFINITY;
    for (int i = blockIdx.x * blockDim.x + threadIdx.x; i < NPTS;
         i += gridDim.x * blockDim.x) {
        m0 = fminf(m0, xyz[i * 3 + 0]);
        m1 = fminf(m1, xyz[i * 3 + 1]);
        m2 = fminf(m2, xyz[i * 3 + 2]);
    }
#pragma unroll
    for (int off = 1; off < 64; off <<= 1) {
        m0 = fminf(m0, __shfl_xor(m0, off, 64));
        m1 = fminf(m1, __shfl_xor(m1, off, 64));
        m2 = fminf(m2, __shfl_xor(m2, off, 64));
    }
    if ((threadIdx.x & 63) == 0) {
        atomicMin(&minbits[0], __float_as_uint(m0)); // xyz >= 0
        atomicMin(&minbits[1], __float_as_uint(m1));
        atomicMin(&minbits[2], __float_as_uint(m2));
    }
}

// ------------------------------------------------------------- quantize xyz
__global__ void xq_kernel(const float* __restrict__ xyz,
                          const int* __restrict__ sort_idx,
                          const unsigned int* __restrict__ minbits,
                          int* __restrict__ xq) {
    int n = blockIdx.x * blockDim.x + threadIdx.x;
    if (n >= NPTS) return;
    int orig = sort_idx[n];
#pragma unroll
    for (int t = 0; t < 3; ++t) {
        float mn = __uint_as_float(minbits[t]);
        float v  = xyz[orig * 3 + t] - mn;   // >= 0
        float md = fmodf(v, WIN);            // == np.mod for non-negative
        float q  = floorf(md / QUANT);
        xq[n * 3 + t] = (int)q;
    }
}

// ----------------------------------------------- pack (key, rel0..2) per pair
__global__ void relpack_kernel(const int* __restrict__ idx1,
                               const int* __restrict__ xq,
                               unsigned int* __restrict__ pairs) {
    int m = blockIdx.x * blockDim.x + threadIdx.x;
    if (m >= NPTS * KNB) return;
    int n = m >> 4;
    int key = idx1[m];
    int r0 = xq[n * 3 + 0] - xq[key * 3 + 0] + 24; r0 = min(max(r0, 0), T2C - 1);
    int r1 = xq[n * 3 + 1] - xq[key * 3 + 1] + 24; r1 = min(max(r1, 0), T2C - 1);
    int r2 = xq[n * 3 + 2] - xq[key * 3 + 2] + 24; r2 = min(max(r2, 0), T2C - 1);
    pairs[m] = (unsigned)key | ((unsigned)r0 << 14) | ((unsigned)r1 << 20) |
               ((unsigned)r2 << 26);
}

// ------------------------ fused prep: feats gather->bf16, weight packs, biases
// Per-head reordered tables: Th[h][jr][d] = T[(jr*6 + h)*64 + d], jr=l*3+t<147
#define G0 (NPTS * CDIM / 4)       // featsbf float4 groups
#define G1 (3 * CDIM * CDIM)       // Wall (q|k|v weight rows)
#define G2 (CDIM * CDIM)           // Wpbf
#define G3 (NH * THR * HDIM)       // Tvh (per-head reordered, f32)
#define G6 (NH * THR * HDIM)       // Tqh (bf16)
#define G7 (NH * THR * HDIM)       // Tkh (bf16)
#define G4 (3 * CDIM)              // bfull
#define G5 (CDIM)                  // bproj
__global__ void prep_kernel(const float* __restrict__ feats,
                            const int* __restrict__ sortix,
                            const float* __restrict__ Wq,
                            const float* __restrict__ Wk,
                            const float* __restrict__ Wv,
                            const float* __restrict__ Wp,
                            const float* __restrict__ bq,
                            const float* __restrict__ bk,
                            const float* __restrict__ bv,
                            const float* __restrict__ bp,
                            const float* __restrict__ Tv,
                            const float* __restrict__ Tq,
                            const float* __restrict__ Tk,
                            unsigned short* __restrict__ featsbf,
                            unsigned short* __restrict__ Wall,
                            unsigned short* __restrict__ Wpbf,
                            float* __restrict__ Tvh,
                            unsigned short* __restrict__ Tqh,
                            unsigned short* __restrict__ Tkh,
                            float* __restrict__ bfull,
                            float* __restrict__ bproj) {
    int i = blockIdx.x * blockDim.x + threadIdx.x;
    if (i < G0) {
        int n  = i / (CDIM / 4);
        int c4 = (i % (CDIM / 4)) * 4;
        const float4 v = *(const float4*)&feats[(size_t)sortix[n] * CDIM + c4];
        ushort4v o;
        o.x = f2bf(v.x); o.y = f2bf(v.y); o.z = f2bf(v.z); o.w = f2bf(v.w);
        *(ushort4v*)&featsbf[(size_t)n * CDIM + c4] = o;
        return;
    }
    i -= G0;
    if (i < G1) {
        int j = i / CDIM, k = i % CDIM;
        float v = (j < 384) ? Wq[j * CDIM + k]
                : (j < 768) ? Wk[(j - 384) * CDIM + k]
                            : Wv[(j - 768) * CDIM + k];
        Wall[i] = f2bf(v);
        return;
    }
    i -= G1;
    if (i < G2) { Wpbf[i] = f2bf(Wp[i]); return; }
    i -= G2;
    if (i < G3) {
        int jr = (i / HDIM) % THR, d = i % HDIM, h = i / (THR * HDIM);
        Tvh[i] = (jr < NL3T) ? Tv[(size_t)(jr * 6 + h) * HDIM + d] : 0.0f;
        return;
    }
    i -= G3;
    if (i < G6) {
        int jr = (i / HDIM) % THR, d = i % HDIM, h = i / (THR * HDIM);
        Tqh[i] = (jr < NL3T) ? f2bf(Tq[(size_t)(jr * 6 + h) * HDIM + d])
                             : (unsigned short)0;
        return;
    }
    i -= G6;
    if (i < G7) {
        int jr = (i / HDIM) % THR, d = i % HDIM, h = i / (THR * HDIM);
        Tkh[i] = (jr < NL3T) ? f2bf(Tk[(size_t)(jr * 6 + h) * HDIM + d])
                             : (unsigned short)0;
        return;
    }
    i -= G7;
    if (i < G4) {
        bfull[i] = (i < 384) ? bq[i] : (i < 768) ? bk[i - 384] : bv[i - 768];
        return;
    }
    i -= G4;
    if (i < G5) { bproj[i] = bp[i]; }
}

// ------------------------------------------------------ fused bf16 MFMA GEMM
// 128x128 tile, 256 threads (4 waves), bijective XCD-swizzled grid.
// mode 0: A=featsbf, W=Wall [1152 x 384] -> qh (x SCALE) / kvh head-major
// mode 1: A=xb,      W=Wpbf [384 x 384]  -> out f32
__global__ __launch_bounds__(256) void gemm_big(
    const unsigned short* __restrict__ Abf,
    const unsigned short* __restrict__ Wmat,
    const float* __restrict__ bias,
    int mode,
    unsigned char* __restrict__ qh8, unsigned char* __restrict__ kvh8,
    float* __restrict__ outf) {
    __shared__ unsigned short As[128 * 64];
    __shared__ unsigned short Bs[128 * 64];
    const int tid  = threadIdx.x;
    const int lane = tid & 63;
    const int w    = tid >> 6;
    const int wm   = w >> 1, wn = w & 1;

    // bijective XCD-aware swizzle (m204)
    const int nwg  = gridDim.x * gridDim.y;
    const int orig = blockIdx.y * gridDim.x + blockIdx.x;
    const int qq   = nwg >> 3, rr = nwg & 7;
    const int xcd  = orig & 7, idx = orig >> 3;
    const int wg   = (xcd < rr ? xcd * (qq + 1) : rr * (qq + 1) + (xcd - rr) * qq) + idx;
    const int jn0  = (wg % gridDim.x) * 128;   // column tile (fast-moving)
    const int m0   = (wg / gridDim.x) * 128;   // row tile

    floatx4 acc[4][4];
#pragma unroll
    for (int i = 0; i < 4; ++i)
#pragma unroll
        for (int j = 0; j < 4; ++j) acc[i][j] = (floatx4)0.0f;

    for (int kt = 0; kt < 6; ++kt) {
        const int k0 = kt * 64;
#pragma unroll
        for (int q = 0; q < 4; ++q) {
            const int s    = w * 4 + q;            // 1KB segment id
            const int row  = s * 8 + (lane >> 3);
            const int col  = (lane & 7) * 8;
            const unsigned short* ga = Abf  + (size_t)(m0  + row) * CDIM + k0 + col;
            const unsigned short* gb = Wmat + (size_t)(jn0 + row) * CDIM + k0 + col;
            __builtin_amdgcn_global_load_lds(
                (const __attribute__((address_space(1))) void*)ga,
                (__attribute__((address_space(3))) void*)&As[s * 512], 16, 0, 0);
            __builtin_amdgcn_global_load_lds(
                (const __attribute__((address_space(1))) void*)gb,
                (__attribute__((address_space(3))) void*)&Bs[s * 512], 16, 0, 0);
        }
        __syncthreads();
#pragma unroll
        for (int ks = 0; ks < 2; ++ks) {
            short8 a[4], b[4];
#pragma unroll
            for (int mi = 0; mi < 4; ++mi) {
                int row = wm * 64 + mi * 16 + (lane & 15);
                a[mi] = *(const short8*)&As[row * 64 + ks * 32 + (lane >> 4) * 8];
            }
#pragma unroll
            for (int ni = 0; ni < 4; ++ni) {
                int jr = wn * 64 + ni * 16 + (lane & 15);
                b[ni] = *(const short8*)&Bs[jr * 64 + ks * 32 + (lane >> 4) * 8];
            }
            // swapped operands: acc frag = 4 consecutive output cols of one row
#pragma unroll
            for (int mi = 0; mi < 4; ++mi)
#pragma unroll
                for (int ni = 0; ni < 4; ++ni)
                    acc[mi][ni] = __builtin_amdgcn_mfma_f32_16x16x32_bf16(
                        b[ni], a[mi], acc[mi][ni], 0, 0, 0);
        }
        __syncthreads();
    }

#pragma unroll
    for (int mi = 0; mi < 4; ++mi) {
        const int n = m0 + wm * 64 + mi * 16 + (lane & 15);
#pragma unroll
        for (int ni = 0; ni < 4; ++ni) {
            const int jjb = jn0 + wn * 64 + ni * 16 + (lane >> 4) * 4;
            const float4 b4 = *(const float4*)&bias[jjb];
            const float v0 = acc[mi][ni][0] + b4.x;
            const float v1 = acc[mi][ni][1] + b4.y;
            const float v2 = acc[mi][ni][2] + b4.z;
            const float v3 = acc[mi][ni][3] + b4.w;
            if (mode == 0) {
                if (jjb < 384) {                    // q -> qh (x QSCALE)
                    const int h = jjb >> 6, d = jjb & 63;
                    ushort4v o;
                    o.x = f2bf(v0 * QSCALE); o.y = f2bf(v1 * QSCALE);
                    o.z = f2bf(v2 * QSCALE); o.w = f2bf(v3 * QSCALE);
                    *(ushort4v*)(qh8 + ((size_t)h * NPTS + n) * 128 + d * 2) = o;
                } else {
                    const int jj = (jjb < 768) ? jjb - 384 : jjb - 768;
                    const int h = jj >> 6, d = jj & 63;
                    const int slot = (jjb < 768) ? 0 : 128;   // k | v
                    ushort4v o;
                    o.x = f2bf(v0); o.y = f2bf(v1);
                    o.z = f2bf(v2); o.w = f2bf(v3);
                    *(ushort4v*)(kvh8 + ((size_t)h * NPTS + n) * KVROW + slot + d * 2) = o;
                }
            } else {
                float4 o; o.x = v0; o.y = v1; o.z = v2; o.w = v3;
                *(float4*)&outf[(size_t)n * CDIM + jjb] = o;
            }
        }
    }
}

// --------------------------- per-head dq low-rank GEMM (K=64, MFMA)
// grid (NPTS/128, NH).  dq[h][n][jr] = DQS * q[n,h,:].Tqh[h][jr,:]
__global__ __launch_bounds__(256) void dq_kernel(
    const unsigned char* __restrict__ qh8,
    const unsigned short* __restrict__ Tqh,
    unsigned char* __restrict__ dqh) {
    __shared__ unsigned short As[128 * 64];   // q head-slices (n-tile)
    __shared__ unsigned short Bs[THR * 64];   // Tq rows (jr 0..159)
    const int tid  = threadIdx.x;
    const int lane = tid & 63;
    const int w    = tid >> 6;
    const int wm   = w >> 1, wn = w & 1;
    const int h    = blockIdx.y;
    const unsigned char* srcb = qh8 + (size_t)h * NPTS * 128;
    unsigned char* dst = dqh + (size_t)h * NPTS * THR;
    const unsigned short* T = Tqh + (size_t)h * THR * HDIM;
    const int m0 = blockIdx.x * 128;

#pragma unroll
    for (int q = 0; q < 4; ++q) {          // A: 16 x 1KB segments
        const int s   = w * 4 + q;
        const int row = s * 8 + (lane >> 3);
        const unsigned char* ga = srcb + (size_t)(m0 + row) * 128 + (lane & 7) * 16;
        __builtin_amdgcn_global_load_lds(
            (const __attribute__((address_space(1))) void*)ga,
            (__attribute__((address_space(3))) void*)&As[s * 512], 16, 0, 0);
    }
#pragma unroll
    for (int q = 0; q < 5; ++q) {          // B: 20 x 1KB segments (160 rows)
        const int s   = w * 5 + q;
        const int row = s * 8 + (lane >> 3);
        const unsigned short* gb = T + (size_t)row * HDIM + (lane & 7) * 8;
        __builtin_amdgcn_global_load_lds(
            (const __attribute__((address_space(1))) void*)gb,
            (__attribute__((address_space(3))) void*)&Bs[s * 512], 16, 0, 0);
    }
    __syncthreads();

    floatx4 acc[4][5];
#pragma unroll
    for (int i = 0; i < 4; ++i)
#pragma unroll
        for (int j = 0; j < 5; ++j) acc[i][j] = (floatx4)0.0f;

#pragma unroll
    for (int ks = 0; ks < 2; ++ks) {
        short8 a[4], b[5];
#pragma unroll
        for (int mi = 0; mi < 4; ++mi) {
            int row = wm * 64 + mi * 16 + (lane & 15);
            a[mi] = *(const short8*)&As[row * 64 + ks * 32 + (lane >> 4) * 8];
        }
#pragma unroll
        for (int ni = 0; ni < 5; ++ni) {
            int jr = wn * 80 + ni * 16 + (lane & 15);
            b[ni] = *(const short8*)&Bs[jr * 64 + ks * 32 + (lane >> 4) * 8];
        }
#pragma unroll
        for (int mi = 0; mi < 4; ++mi)
#pragma unroll
            for (int ni = 0; ni < 5; ++ni)
                acc[mi][ni] = __builtin_amdgcn_mfma_f32_16x16x32_bf16(
                    b[ni], a[mi], acc[mi][ni], 0, 0, 0);
    }

#pragma unroll
    for (int mi = 0; mi < 4; ++mi) {
        const int n = m0 + wm * 64 + mi * 16 + (lane & 15);
#pragma unroll
        for (int ni = 0; ni < 5; ++ni) {
            const int jr0 = wn * 80 + ni * 16 + (lane >> 4) * 4;
            int u = __builtin_amdgcn_cvt_pk_fp8_f32(acc[mi][ni][0] * DQS,
                                                    acc[mi][ni][1] * DQS, 0, false);
            u = __builtin_amdgcn_cvt_pk_fp8_f32(acc[mi][ni][2] * DQS,
                                                acc[mi][ni][3] * DQS, u, true);
            *(unsigned int*)(dst + (size_t)n * THR + jr0) = (unsigned)u;
        }
    }
}

// -------------------------------------------------- attention main pass
// grid (NPTS/4, NH) swizzled; block 256 = 4 waves; wave = (query, head).
// lane = pp*16 + c. k/v bf16 gathers (1 line each); dq folded pre-butterfly
// (c<3, L1-hot fp8 row); dk recomputed as k.(Tk[jr0]+Tk[jr1]+Tk[jr2])
// from the 20KB/head L1-hot bf16 Tk table — no dkh gather, no L2 thrash.
__global__ __launch_bounds__(256) void attn_kernel(
    const unsigned char* __restrict__ qh8,
    const unsigned char* __restrict__ kvh8,
    const unsigned int* __restrict__ pairs,
    const unsigned char* __restrict__ dqh,
    const unsigned short* __restrict__ Tkh,
    const float* __restrict__ Tvh,
    const int* __restrict__ sortix,
    unsigned short* __restrict__ xb) {
    int nb, h;
    swz_nh(nb, h);
    const int n = nb * 4 + (threadIdx.x >> 6);
    const int lane = threadIdx.x & 63;
    const int pp = lane >> 4, c = lane & 15;
    const int c8 = c * 8;

    const unsigned char* kvb = kvh8 + (size_t)h * NPTS * KVROW;        // uniform
    const float* Tvb = Tvh + (size_t)h * THR * HDIM;                   // uniform
    const unsigned char* tkb =
        (const unsigned char*)Tkh + (size_t)h * THR * 128;             // uniform
    const unsigned char* dqn = dqh + ((size_t)h * NPTS + n) * THR;     // uniform

    const uint2 qw = *(const uint2*)(qh8 + ((size_t)h * NPTS + n) * 128 + c8);
    const float2v q01 = bfpair(qw.x), q23 = bfpair(qw.y);

    unsigned int pv[4];
#pragma unroll
    for (int g = 0; g < 4; ++g) pv[g] = pairs[n * KNB + g * 4 + pp];

    int koff[4], t0o[4], t1o[4], t2o[4];
#pragma unroll
    for (int g = 0; g < 4; ++g) {
        koff[g] = (int)(pv[g] & 0x3FFFu) * KVROW + c8;
        t0o[g]  = (int)((pv[g] >> 14) & 63u) * 192 + c * 4;        // f32 idx, t=0
        t1o[g]  = (int)((pv[g] >> 20) & 63u) * 192 + 64 + c * 4;   // t=1
        t2o[g]  = (int)(pv[g] >> 26) * 192 + 128 + c * 4;          // t=2
    }
    // Tk bf16 byte offset == 2 x Tv f32 index (row 128B vs 64 floats)

    float lg[4];
#pragma unroll
    for (int g = 0; g < 4; ++g) {
        const uint2 kw = *(const uint2*)(kvb + koff[g]);
        const uint2 w0 = *(const uint2*)(tkb + (t0o[g] << 1));
        const uint2 w1 = *(const uint2*)(tkb + (t1o[g] << 1));
        const uint2 w2 = *(const uint2*)(tkb + (t2o[g] << 1));
        const float2v k01 = bfpair(kw.x), k23 = bfpair(kw.y);
        const float2v ts01 = bfpair(w0.x) + bfpair(w1.x) + bfpair(w2.x);
        const float2v ts23 = bfpair(w0.y) + bfpair(w1.y) + bfpair(w2.y);
        float2v d = (q01 + ts01) * k01 + (q23 + ts23) * k23;
        float part = d.x + d.y;
        // fold dq rel-pos term pre-butterfly (summed by the reduce below)
        if (c < 3) {
            const int r  = (int)((pv[g] >> (14 + 6 * c)) & 63u);
            part += f8tof(dqn[r * 3 + c]) * DQSINV;
        }
        lg[g] = part;
    }
#pragma unroll
    for (int m = 1; m <= 8; m <<= 1)
#pragma unroll
        for (int g = 0; g < 4; ++g) lg[g] += __shfl_xor(lg[g], m, 64);

    // softmax over 16 pairs (4 in-lane x 4 pp-groups)
    float mx = fmaxf(fmaxf(lg[0], lg[1]), fmaxf(lg[2], lg[3]));
    mx = fmaxf(mx, __shfl_xor(mx, 16, 64));
    mx = fmaxf(mx, __shfl_xor(mx, 32, 64));
    float e[4], s = 0.f;
#pragma unroll
    for (int g = 0; g < 4; ++g) { e[g] = __expf(lg[g] - mx); s += e[g]; }
    s += __shfl_xor(s, 16, 64);
    s += __shfl_xor(s, 32, 64);
    const float inv = __builtin_amdgcn_rcpf(s);

    floatx4 xa = (floatx4)0.0f;
#pragma unroll
    for (int g = 0; g < 4; ++g) {
        const float wgt = e[g] * inv;
        const uint2 vw = *(const uint2*)(kvb + koff[g] + 128);
        const float2v v01 = bfpair(vw.x), v23 = bfpair(vw.y);
        floatx4 vv;
        vv[0] = v01.x; vv[1] = v01.y; vv[2] = v23.x; vv[3] = v23.y;
        const floatx4 a0 = *(const floatx4*)&Tvb[t0o[g]];
        const floatx4 a1 = *(const floatx4*)&Tvb[t1o[g]];
        const floatx4 a2 = *(const floatx4*)&Tvb[t2o[g]];
        xa += wgt * (vv + a0 + a1 + a2);   // f32 table: only v needs unpack
    }
    float xa0 = xa[0], xa1 = xa[1], xa2 = xa[2], xa3 = xa[3];
#pragma unroll
    for (int m = 16; m <= 32; m <<= 1) {
        xa0 += __shfl_xor(xa0, m, 64);
        xa1 += __shfl_xor(xa1, m, 64);
        xa2 += __shfl_xor(xa2, m, 64);
        xa3 += __shfl_xor(xa3, m, 64);
    }
    if (pp == 0) {
        const int dst = sortix[n]; // unsort
        ushort4v o;
        o.x = f2bf(xa0); o.y = f2bf(xa1); o.z = f2bf(xa2); o.w = f2bf(xa3);
        *(ushort4v*)&xb[(size_t)dst * CDIM + h * HDIM + c * 4] = o;
    }
}

// ---------------------------------------------------------------------------
extern "C" void kernel_launch(void* const* d_in, const int* in_sizes, int n_in,
                              void* d_out, int out_size, void* d_ws,
                              size_t ws_size, hipStream_t stream) {
    const float* feats  = (const float*)d_in[0];
    const float* xyz    = (const float*)d_in[1];
    const int*   index1 = (const int*)d_in[4];
    const int*   sortix = (const int*)d_in[5];
    const float* Wq = (const float*)d_in[6];
    const float* bq = (const float*)d_in[7];
    const float* Wk = (const float*)d_in[8];
    const float* bk = (const float*)d_in[9];
    const float* Wv = (const float*)d_in[10];
    const float* bv = (const float*)d_in[11];
    const float* Wp = (const float*)d_in[12];
    const float* bp = (const float*)d_in[13];
    const float* Tq = (const float*)d_in[14];
    const float* Tk = (const float*)d_in[15];
    const float* Tv = (const float*)d_in[16];
    float* out = (float*)d_out;

    char* ws = (char*)d_ws;
    size_t off = 0;
    auto alloc = [&](size_t bytes) -> void* {
        void* p = ws + off;
        off = (off + bytes + 255) & ~(size_t)255;
        return p;
    };
    unsigned short* featsbf = (unsigned short*)alloc((size_t)NPTS * CDIM * 2); // reused as xb
    unsigned short* Wall    = (unsigned short*)alloc((size_t)NXC * CDIM * 2);
    unsigned short* Wpbf    = (unsigned short*)alloc((size_t)CDIM * CDIM * 2);
    float*          Tvh     = (float*)alloc((size_t)NH * THR * HDIM * 4);
    unsigned short* Tqh     = (unsigned short*)alloc((size_t)NH * THR * HDIM * 2);
    unsigned short* Tkh     = (unsigned short*)alloc((size_t)NH * THR * HDIM * 2);
    float*          bfull   = (float*)alloc((size_t)NXC * sizeof(float));
    float*          bproj   = (float*)alloc((size_t)CDIM * sizeof(float));
    unsigned char*  qh8     = (unsigned char*)alloc((size_t)NH * NPTS * 128);
    unsigned char*  kvh8    = (unsigned char*)alloc((size_t)NH * NPTS * KVROW);
    unsigned char*  dqh     = (unsigned char*)alloc((size_t)NH * NPTS * THR);
    unsigned int*   pairs   = (unsigned int*)alloc((size_t)NPTS * KNB * 4);
    int*            xq      = (int*)alloc((size_t)NPTS * 3 * sizeof(int));
    unsigned int*   minbits = (unsigned int*)alloc(16);
    unsigned short* xb      = featsbf; // featsbf dead after gemm0

    // init minbits to 0x7f7f7f7f (~3.4e38) — valid "+inf" stand-in for xyz<=240
    hipMemsetAsync(minbits, 0x7f, 16, stream);
    min_kernel<<<128, 256, 0, stream>>>(xyz, minbits);
    xq_kernel<<<(NPTS + 255) / 256, 256, 0, stream>>>(xyz, sortix, minbits, xq);
    relpack_kernel<<<(NPTS * KNB + 255) / 256, 256, 0, stream>>>(index1, xq, pairs);

    const int prep_total = G0 + G1 + G2 + G3 + G6 + G7 + G4 + G5;
    prep_kernel<<<(prep_total + 255) / 256, 256, 0, stream>>>(
        feats, sortix, Wq, Wk, Wv, Wp, bq, bk, bv, bp, Tv, Tq, Tk,
        featsbf, Wall, Wpbf, Tvh, Tqh, Tkh, bfull, bproj);

    dim3 g0(NXC / 128, NPTS / 128);
    gemm_big<<<g0, 256, 0, stream>>>(featsbf, Wall, bfull, 0, qh8, kvh8,
                                     (float*)nullptr);

    dim3 gd(NPTS / 128, NH);
    dq_kernel<<<gd, 256, 0, stream>>>(qh8, Tqh, dqh);

    dim3 ga(NPTS / 4, NH);
    attn_kernel<<<ga, 256, 0, stream>>>(qh8, kvh8, pairs, dqh, Tkh, Tvh,
                                        sortix, xb);

    dim3 g1(CDIM / 128, NPTS / 128);
    gemm_big<<<g1, 256, 0, stream>>>(xb, Wpbf, bproj, 1, (unsigned char*)nullptr,
                                     (unsigned char*)nullptr, out);
}

// Round 19
// 203.629 us; speedup vs baseline: 1.0677x; 1.0677x over previous
//
#include <hip/hip_runtime.h>
#include <hip/hip_bf16.h>
#include <cstdint>
#include <cstddef>

#define NPTS 16000
#define KNB  16
#define CDIM 384
#define NH   6
#define HDIM 64
#define T2C  49
#define NL3T 147             // 49*3 table rows
#define THR  160             // per-head table rows padded (147 used)
#define NXC  1152            // q|k|v GEMM output cols
#define KVROW 256            // kvh row: interleaved [c*16]=k[4c..4c+3]|v[4c..4c+3]
// head-major buffers:
//   qh [h][n][128B bf16]   kh [h][n][128B bf16] (contiguous k, for dqdk)
//   kvh[h][n][256B] (k|v interleaved 8B:8B)   dqh/dkh[h][n][160B fp8x8]
//   tqk[h][n][16] bf16     Tvh f32 [h][160][64] (L2-hot)

static constexpr float WIN    = 6.0f;
static constexpr float QUANT  = 0.24f;
static constexpr float QSCALE = 0.125f; // 64^-0.5
static constexpr float DQS    = 8.0f;   // fp8 range pre-scale for dq/dk
static constexpr float DQSINV = 0.125f;

typedef __attribute__((ext_vector_type(8))) short short8;
typedef __attribute__((ext_vector_type(4))) float floatx4;
typedef __attribute__((ext_vector_type(4))) unsigned short ushort4v;
typedef __attribute__((ext_vector_type(2))) float float2v;

__device__ inline unsigned short f2bf(float x) {
    unsigned int u = __float_as_uint(x);
    unsigned int r = (u + 0x7fffu + ((u >> 16) & 1u)) >> 16;
    return (unsigned short)r;
}
__device__ inline float bf2f(unsigned short b) {
    return __uint_as_float(((unsigned int)b) << 16);
}
__device__ inline float f8tof(unsigned char b) {
    return __builtin_amdgcn_cvt_f32_fp8((int)b, 0);
}
// unpack a bf16x2 word into {elem0, elem1} as f32 (2 VALU ops)
__device__ inline float2v bfpair(unsigned int w) {
    float2v r;
    r.x = __uint_as_float(w << 16);
    r.y = __uint_as_float(w & 0xffff0000u);
    return r;
}

// bijective XCD-chunked (m204) decode for grid (NPTS/4, NH)
__device__ inline void swz_nh(int& nb, int& h) {
    const int gx   = gridDim.x;
    const int nwg  = gx * NH;
    const int orig = blockIdx.y * gx + blockIdx.x;
    const int q    = nwg >> 3, r = nwg & 7;
    const int xcd  = orig & 7, idx = orig >> 3;
    const int wg   = (xcd < r ? xcd * (q + 1) : r * (q + 1) + (xcd - r) * q) + idx;
    h  = wg / gx;
    nb = wg % gx;
}

// ---------------------------------------------------------------- min reduce
// minbits pre-set to 0x7f7f7f7f (≈3.4e38) via hipMemsetAsync
__global__ void min_kernel(const float* __restrict__ xyz,
                           unsigned int* __restrict__ minbits) {
    float m0 = INFINITY, m1 = INFINITY, m2 = INFINITY;
    for (int i = blockIdx.x * blockDim.x + threadIdx.x; i < NPTS;
         i += gridDim.x * blockDim.x) {
        m0 = fminf(m0, xyz[i * 3 + 0]);
        m1 = fminf(m1, xyz[i * 3 + 1]);
        m2 = fminf(m2, xyz[i * 3 + 2]);
    }
#pragma unroll
    for (int off = 1; off < 64; off <<= 1) {
        m0 = fminf(m0, __shfl_xor(m0, off, 64));
        m1 = fminf(m1, __shfl_xor(m1, off, 64));
        m2 = fminf(m2, __shfl_xor(m2, off, 64));
    }
    if ((threadIdx.x & 63) == 0) {
        atomicMin(&minbits[0], __float_as_uint(m0)); // xyz >= 0
        atomicMin(&minbits[1], __float_as_uint(m1));
        atomicMin(&minbits[2], __float_as_uint(m2));
    }
}

// ------------------------------------------------------------- quantize xyz
__global__ void xq_kernel(const float* __restrict__ xyz,
                          const int* __restrict__ sort_idx,
                          const unsigned int* __restrict__ minbits,
                          int* __restrict__ xq) {
    int n = blockIdx.x * blockDim.x + threadIdx.x;
    if (n >= NPTS) return;
    int orig = sort_idx[n];
#pragma unroll
    for (int t = 0; t < 3; ++t) {
        float mn = __uint_as_float(minbits[t]);
        float v  = xyz[orig * 3 + t] - mn;   // >= 0
        float md = fmodf(v, WIN);            // == np.mod for non-negative
        float q  = floorf(md / QUANT);
        xq[n * 3 + t] = (int)q;
    }
}

// ----------------------------------------------- pack (key, rel0..2) per pair
__global__ void relpack_kernel(const int* __restrict__ idx1,
                               const int* __restrict__ xq,
                               unsigned int* __restrict__ pairs) {
    int m = blockIdx.x * blockDim.x + threadIdx.x;
    if (m >= NPTS * KNB) return;
    int n = m >> 4;
    int key = idx1[m];
    int r0 = xq[n * 3 + 0] - xq[key * 3 + 0] + 24; r0 = min(max(r0, 0), T2C - 1);
    int r1 = xq[n * 3 + 1] - xq[key * 3 + 1] + 24; r1 = min(max(r1, 0), T2C - 1);
    int r2 = xq[n * 3 + 2] - xq[key * 3 + 2] + 24; r2 = min(max(r2, 0), T2C - 1);
    pairs[m] = (unsigned)key | ((unsigned)r0 << 14) | ((unsigned)r1 << 20) |
               ((unsigned)r2 << 26);
}

// ------------------------ fused prep: feats gather->bf16, weight packs, biases
// Per-head reordered tables: Th[h][jr][d] = T[(jr*6 + h)*64 + d], jr=l*3+t<147
#define G0 (NPTS * CDIM / 4)       // featsbf float4 groups
#define G1 (3 * CDIM * CDIM)       // Wall (q|k|v weight rows)
#define G2 (CDIM * CDIM)           // Wpbf
#define G3 (NH * THR * HDIM)       // Tvh (per-head reordered, f32)
#define G6 (NH * THR * HDIM)       // Tqh (bf16)
#define G7 (NH * THR * HDIM)       // Tkh (bf16)
#define G4 (3 * CDIM)              // bfull
#define G5 (CDIM)                  // bproj
__global__ void prep_kernel(const float* __restrict__ feats,
                            const int* __restrict__ sortix,
                            const float* __restrict__ Wq,
                            const float* __restrict__ Wk,
                            const float* __restrict__ Wv,
                            const float* __restrict__ Wp,
                            const float* __restrict__ bq,
                            const float* __restrict__ bk,
                            const float* __restrict__ bv,
                            const float* __restrict__ bp,
                            const float* __restrict__ Tv,
                            const float* __restrict__ Tq,
                            const float* __restrict__ Tk,
                            unsigned short* __restrict__ featsbf,
                            unsigned short* __restrict__ Wall,
                            unsigned short* __restrict__ Wpbf,
                            float* __restrict__ Tvh,
                            unsigned short* __restrict__ Tqh,
                            unsigned short* __restrict__ Tkh,
                            float* __restrict__ bfull,
                            float* __restrict__ bproj) {
    int i = blockIdx.x * blockDim.x + threadIdx.x;
    if (i < G0) {
        int n  = i / (CDIM / 4);
        int c4 = (i % (CDIM / 4)) * 4;
        const float4 v = *(const float4*)&feats[(size_t)sortix[n] * CDIM + c4];
        ushort4v o;
        o.x = f2bf(v.x); o.y = f2bf(v.y); o.z = f2bf(v.z); o.w = f2bf(v.w);
        *(ushort4v*)&featsbf[(size_t)n * CDIM + c4] = o;
        return;
    }
    i -= G0;
    if (i < G1) {
        int j = i / CDIM, k = i % CDIM;
        float v = (j < 384) ? Wq[j * CDIM + k]
                : (j < 768) ? Wk[(j - 384) * CDIM + k]
                            : Wv[(j - 768) * CDIM + k];
        Wall[i] = f2bf(v);
        return;
    }
    i -= G1;
    if (i < G2) { Wpbf[i] = f2bf(Wp[i]); return; }
    i -= G2;
    if (i < G3) {
        int jr = (i / HDIM) % THR, d = i % HDIM, h = i / (THR * HDIM);
        Tvh[i] = (jr < NL3T) ? Tv[(size_t)(jr * 6 + h) * HDIM + d] : 0.0f;
        return;
    }
    i -= G3;
    if (i < G6) {
        int jr = (i / HDIM) % THR, d = i % HDIM, h = i / (THR * HDIM);
        Tqh[i] = (jr < NL3T) ? f2bf(Tq[(size_t)(jr * 6 + h) * HDIM + d])
                             : (unsigned short)0;
        return;
    }
    i -= G6;
    if (i < G7) {
        int jr = (i / HDIM) % THR, d = i % HDIM, h = i / (THR * HDIM);
        Tkh[i] = (jr < NL3T) ? f2bf(Tk[(size_t)(jr * 6 + h) * HDIM + d])
                             : (unsigned short)0;
        return;
    }
    i -= G7;
    if (i < G4) {
        bfull[i] = (i < 384) ? bq[i] : (i < 768) ? bk[i - 384] : bv[i - 768];
        return;
    }
    i -= G4;
    if (i < G5) { bproj[i] = bp[i]; }
}

// ------------------------------------------------------ fused bf16 MFMA GEMM
// 128x128 tile, 256 threads (4 waves), bijective XCD-swizzled grid.
// mode 0: A=featsbf, W=Wall [1152x384] -> qh / kh / kvh(interleaved) head-major
// mode 1: A=xb,      W=Wpbf [384x384]  -> out f32
__global__ __launch_bounds__(256) void gemm_big(
    const unsigned short* __restrict__ Abf,
    const unsigned short* __restrict__ Wmat,
    const float* __restrict__ bias,
    int mode,
    unsigned char* __restrict__ qh8, unsigned char* __restrict__ kh8,
    unsigned char* __restrict__ kvh8, float* __restrict__ outf) {
    __shared__ unsigned short As[128 * 64];
    __shared__ unsigned short Bs[128 * 64];
    const int tid  = threadIdx.x;
    const int lane = tid & 63;
    const int w    = tid >> 6;
    const int wm   = w >> 1, wn = w & 1;

    // bijective XCD-aware swizzle (m204)
    const int nwg  = gridDim.x * gridDim.y;
    const int orig = blockIdx.y * gridDim.x + blockIdx.x;
    const int qq   = nwg >> 3, rr = nwg & 7;
    const int xcd  = orig & 7, idx = orig >> 3;
    const int wg   = (xcd < rr ? xcd * (qq + 1) : rr * (qq + 1) + (xcd - rr) * qq) + idx;
    const int jn0  = (wg % gridDim.x) * 128;   // column tile (fast-moving)
    const int m0   = (wg / gridDim.x) * 128;   // row tile

    floatx4 acc[4][4];
#pragma unroll
    for (int i = 0; i < 4; ++i)
#pragma unroll
        for (int j = 0; j < 4; ++j) acc[i][j] = (floatx4)0.0f;

    for (int kt = 0; kt < 6; ++kt) {
        const int k0 = kt * 64;
#pragma unroll
        for (int q = 0; q < 4; ++q) {
            const int s    = w * 4 + q;            // 1KB segment id
            const int row  = s * 8 + (lane >> 3);
            const int col  = (lane & 7) * 8;
            const unsigned short* ga = Abf  + (size_t)(m0  + row) * CDIM + k0 + col;
            const unsigned short* gb = Wmat + (size_t)(jn0 + row) * CDIM + k0 + col;
            __builtin_amdgcn_global_load_lds(
                (const __attribute__((address_space(1))) void*)ga,
                (__attribute__((address_space(3))) void*)&As[s * 512], 16, 0, 0);
            __builtin_amdgcn_global_load_lds(
                (const __attribute__((address_space(1))) void*)gb,
                (__attribute__((address_space(3))) void*)&Bs[s * 512], 16, 0, 0);
        }
        __syncthreads();
#pragma unroll
        for (int ks = 0; ks < 2; ++ks) {
            short8 a[4], b[4];
#pragma unroll
            for (int mi = 0; mi < 4; ++mi) {
                int row = wm * 64 + mi * 16 + (lane & 15);
                a[mi] = *(const short8*)&As[row * 64 + ks * 32 + (lane >> 4) * 8];
            }
#pragma unroll
            for (int ni = 0; ni < 4; ++ni) {
                int jr = wn * 64 + ni * 16 + (lane & 15);
                b[ni] = *(const short8*)&Bs[jr * 64 + ks * 32 + (lane >> 4) * 8];
            }
            // swapped operands: acc frag = 4 consecutive output cols of one row
#pragma unroll
            for (int mi = 0; mi < 4; ++mi)
#pragma unroll
                for (int ni = 0; ni < 4; ++ni)
                    acc[mi][ni] = __builtin_amdgcn_mfma_f32_16x16x32_bf16(
                        b[ni], a[mi], acc[mi][ni], 0, 0, 0);
        }
        __syncthreads();
    }

#pragma unroll
    for (int mi = 0; mi < 4; ++mi) {
        const int n = m0 + wm * 64 + mi * 16 + (lane & 15);
#pragma unroll
        for (int ni = 0; ni < 4; ++ni) {
            const int jjb = jn0 + wn * 64 + ni * 16 + (lane >> 4) * 4;
            const float4 b4 = *(const float4*)&bias[jjb];
            const float v0 = acc[mi][ni][0] + b4.x;
            const float v1 = acc[mi][ni][1] + b4.y;
            const float v2 = acc[mi][ni][2] + b4.z;
            const float v3 = acc[mi][ni][3] + b4.w;
            if (mode == 0) {
                if (jjb < 384) {                    // q -> qh (x QSCALE)
                    const int h = jjb >> 6, d = jjb & 63;
                    ushort4v o;
                    o.x = f2bf(v0 * QSCALE); o.y = f2bf(v1 * QSCALE);
                    o.z = f2bf(v2 * QSCALE); o.w = f2bf(v3 * QSCALE);
                    *(ushort4v*)(qh8 + ((size_t)h * NPTS + n) * 128 + d * 2) = o;
                } else if (jjb < 768) {             // k -> kh (contig) + kvh
                    const int jj = jjb - 384;
                    const int h = jj >> 6, d = jj & 63;
                    ushort4v o;
                    o.x = f2bf(v0); o.y = f2bf(v1);
                    o.z = f2bf(v2); o.w = f2bf(v3);
                    *(ushort4v*)(kh8 + ((size_t)h * NPTS + n) * 128 + d * 2) = o;
                    *(ushort4v*)(kvh8 + ((size_t)h * NPTS + n) * KVROW + d * 4) = o;
                } else {                            // v -> kvh interleaved
                    const int jj = jjb - 768;
                    const int h = jj >> 6, d = jj & 63;
                    ushort4v o;
                    o.x = f2bf(v0); o.y = f2bf(v1);
                    o.z = f2bf(v2); o.w = f2bf(v3);
                    *(ushort4v*)(kvh8 + ((size_t)h * NPTS + n) * KVROW + d * 4 + 8) = o;
                }
            } else {
                float4 o; o.x = v0; o.y = v1; o.z = v2; o.w = v3;
                *(float4*)&outf[(size_t)n * CDIM + jjb] = o;
            }
        }
    }
}

// --------------------------- per-head dq/dk low-rank GEMM (K=64, MFMA)
// grid (NPTS/128, NH, 2).  dq[h][n][jr] = DQS * q[n,h,:].Th[h][jr,:]
__global__ __launch_bounds__(256) void dqdk_kernel(
    const unsigned char* __restrict__ qh8,
    const unsigned char* __restrict__ kh8,
    const unsigned short* __restrict__ Tqh,
    const unsigned short* __restrict__ Tkh,
    unsigned char* __restrict__ dqh,
    unsigned char* __restrict__ dkh) {
    __shared__ unsigned short As[128 * 64];   // q/k head-slices (n-tile)
    __shared__ unsigned short Bs[THR * 64];   // Th rows (jr 0..159)
    const int tid  = threadIdx.x;
    const int lane = tid & 63;
    const int w    = tid >> 6;
    const int wm   = w >> 1, wn = w & 1;
    const int h    = blockIdx.y;
    const bool isk = blockIdx.z != 0;
    const unsigned char* srcb = (isk ? kh8 : qh8) + (size_t)h * NPTS * 128;
    unsigned char* dst = (isk ? dkh : dqh) + (size_t)h * NPTS * THR;
    const unsigned short* T = (isk ? Tkh : Tqh) + (size_t)h * THR * HDIM;
    const int m0 = blockIdx.x * 128;

#pragma unroll
    for (int q = 0; q < 4; ++q) {          // A: 16 x 1KB segments
        const int s   = w * 4 + q;
        const int row = s * 8 + (lane >> 3);
        const unsigned char* ga = srcb + (size_t)(m0 + row) * 128 + (lane & 7) * 16;
        __builtin_amdgcn_global_load_lds(
            (const __attribute__((address_space(1))) void*)ga,
            (__attribute__((address_space(3))) void*)&As[s * 512], 16, 0, 0);
    }
#pragma unroll
    for (int q = 0; q < 5; ++q) {          // B: 20 x 1KB segments (160 rows)
        const int s   = w * 5 + q;
        const int row = s * 8 + (lane >> 3);
        const unsigned short* gb = T + (size_t)row * HDIM + (lane & 7) * 8;
        __builtin_amdgcn_global_load_lds(
            (const __attribute__((address_space(1))) void*)gb,
            (__attribute__((address_space(3))) void*)&Bs[s * 512], 16, 0, 0);
    }
    __syncthreads();

    floatx4 acc[4][5];
#pragma unroll
    for (int i = 0; i < 4; ++i)
#pragma unroll
        for (int j = 0; j < 5; ++j) acc[i][j] = (floatx4)0.0f;

#pragma unroll
    for (int ks = 0; ks < 2; ++ks) {
        short8 a[4], b[5];
#pragma unroll
        for (int mi = 0; mi < 4; ++mi) {
            int row = wm * 64 + mi * 16 + (lane & 15);
            a[mi] = *(const short8*)&As[row * 64 + ks * 32 + (lane >> 4) * 8];
        }
#pragma unroll
        for (int ni = 0; ni < 5; ++ni) {
            int jr = wn * 80 + ni * 16 + (lane & 15);
            b[ni] = *(const short8*)&Bs[jr * 64 + ks * 32 + (lane >> 4) * 8];
        }
#pragma unroll
        for (int mi = 0; mi < 4; ++mi)
#pragma unroll
            for (int ni = 0; ni < 5; ++ni)
                acc[mi][ni] = __builtin_amdgcn_mfma_f32_16x16x32_bf16(
                    b[ni], a[mi], acc[mi][ni], 0, 0, 0);
    }

#pragma unroll
    for (int mi = 0; mi < 4; ++mi) {
        const int n = m0 + wm * 64 + mi * 16 + (lane & 15);
#pragma unroll
        for (int ni = 0; ni < 5; ++ni) {
            const int jr0 = wn * 80 + ni * 16 + (lane >> 4) * 4;
            int u = __builtin_amdgcn_cvt_pk_fp8_f32(acc[mi][ni][0] * DQS,
                                                    acc[mi][ni][1] * DQS, 0, false);
            u = __builtin_amdgcn_cvt_pk_fp8_f32(acc[mi][ni][2] * DQS,
                                                acc[mi][ni][3] * DQS, u, true);
            *(unsigned int*)(dst + (size_t)n * THR + jr0) = (unsigned)u;
        }
    }
}

// ----------------------------- tqk pre-pass: per (query, head, pair) table sum
// grid (NPTS/4, NH) swizzled; block 256 = 4 waves (wave = query).
// lane: p = lane>>2 (pair), s = lane&3 (t axis; s==3 idle).
__global__ __launch_bounds__(256) void tqk_kernel(
    const unsigned int* __restrict__ pairs,
    const unsigned char* __restrict__ dqh,
    const unsigned char* __restrict__ dkh,
    unsigned short* __restrict__ tqk) {
    int nb, h;
    swz_nh(nb, h);
    const int n = nb * 4 + (threadIdx.x >> 6);
    const int lane = threadIdx.x & 63;
    const int p = lane >> 2, s = lane & 3;

    const unsigned int pv = pairs[n * KNB + p];
    float v = 0.0f;
    if (s < 3) {
        const int key = (int)(pv & 0x3FFFu);
        const int r = (int)((pv >> (14 + 6 * s)) & 63u);
        const int jr = r * 3 + s;
        v = f8tof(dqh[(size_t)h * NPTS * THR + (size_t)n * THR + jr]) +
            f8tof(dkh[(size_t)h * NPTS * THR + (size_t)key * THR + jr]);
    }
    v += __shfl_xor(v, 1, 64);
    v += __shfl_xor(v, 2, 64);
    if (s == 0)
        tqk[((size_t)h * NPTS + n) * KNB + p] = f2bf(v * DQSINV);
}

// -------------------------------------------------- attention main pass
// grid (NPTS/4, NH) swizzled; block 256 = 4 waves; wave = (query, head).
// lane = pp*16 + c. ONE 16B load per pair fetches k+v (interleaved row);
// Tv f32 (L2-hot); tqr precomputed (tqk pass).
__global__ __launch_bounds__(256) void attn_kernel(
    const unsigned char* __restrict__ qh8,
    const unsigned char* __restrict__ kvh8,
    const unsigned int* __restrict__ pairs,
    const unsigned short* __restrict__ tqk,
    const float* __restrict__ Tvh,
    const int* __restrict__ sortix,
    unsigned short* __restrict__ xb) {
    int nb, h;
    swz_nh(nb, h);
    const int n = nb * 4 + (threadIdx.x >> 6);
    const int lane = threadIdx.x & 63;
    const int pp = lane >> 4, c = lane & 15;

    const unsigned char* kvb = kvh8 + (size_t)h * NPTS * KVROW;        // uniform
    const float* Tvb = Tvh + (size_t)h * THR * HDIM;                   // uniform
    const unsigned short* tqr = tqk + ((size_t)h * NPTS + n) * KNB;

    const uint2 qw = *(const uint2*)(qh8 + ((size_t)h * NPTS + n) * 128 + c * 8);
    const float2v q01 = bfpair(qw.x), q23 = bfpair(qw.y);

    unsigned int pv[4];
#pragma unroll
    for (int g = 0; g < 4; ++g) pv[g] = pairs[n * KNB + g * 4 + pp];

    int t0o[4], t1o[4], t2o[4];
    uint2 vw[4];
    float lg[4];
#pragma unroll
    for (int g = 0; g < 4; ++g) {
        t0o[g] = (int)((pv[g] >> 14) & 63u) * 192 + c * 4;        // f32 idx, t=0
        t1o[g] = (int)((pv[g] >> 20) & 63u) * 192 + 64 + c * 4;   // t=1
        t2o[g] = (int)(pv[g] >> 26) * 192 + 128 + c * 4;          // t=2
        const uint4 kv4 =
            *(const uint4*)(kvb + (int)(pv[g] & 0x3FFFu) * KVROW + c * 16);
        float2v d = q01 * bfpair(kv4.x) + q23 * bfpair(kv4.y);
        lg[g] = d.x + d.y;
        vw[g].x = kv4.z; vw[g].y = kv4.w;   // v half, used after softmax
    }
#pragma unroll
    for (int m = 1; m <= 8; m <<= 1)
#pragma unroll
        for (int g = 0; g < 4; ++g) lg[g] += __shfl_xor(lg[g], m, 64);
#pragma unroll
    for (int g = 0; g < 4; ++g) lg[g] += bf2f(tqr[g * 4 + pp]);

    // softmax over 16 pairs (4 in-lane x 4 pp-groups)
    float mx = fmaxf(fmaxf(lg[0], lg[1]), fmaxf(lg[2], lg[3]));
    mx = fmaxf(mx, __shfl_xor(mx, 16, 64));
    mx = fmaxf(mx, __shfl_xor(mx, 32, 64));
    float e[4], s = 0.f;
#pragma unroll
    for (int g = 0; g < 4; ++g) { e[g] = __expf(lg[g] - mx); s += e[g]; }
    s += __shfl_xor(s, 16, 64);
    s += __shfl_xor(s, 32, 64);
    const float inv = __builtin_amdgcn_rcpf(s);

    floatx4 xa = (floatx4)0.0f;
#pragma unroll
    for (int g = 0; g < 4; ++g) {
        const float wgt = e[g] * inv;
        const float2v v01 = bfpair(vw[g].x), v23 = bfpair(vw[g].y);
        floatx4 vv;
        vv[0] = v01.x; vv[1] = v01.y; vv[2] = v23.x; vv[3] = v23.y;
        const floatx4 a0 = *(const floatx4*)&Tvb[t0o[g]];
        const floatx4 a1 = *(const floatx4*)&Tvb[t1o[g]];
        const floatx4 a2 = *(const floatx4*)&Tvb[t2o[g]];
        xa += wgt * (vv + a0 + a1 + a2);
    }
    float xa0 = xa[0], xa1 = xa[1], xa2 = xa[2], xa3 = xa[3];
#pragma unroll
    for (int m = 16; m <= 32; m <<= 1) {
        xa0 += __shfl_xor(xa0, m, 64);
        xa1 += __shfl_xor(xa1, m, 64);
        xa2 += __shfl_xor(xa2, m, 64);
        xa3 += __shfl_xor(xa3, m, 64);
    }
    if (pp == 0) {
        const int dst = sortix[n]; // unsort
        ushort4v o;
        o.x = f2bf(xa0); o.y = f2bf(xa1); o.z = f2bf(xa2); o.w = f2bf(xa3);
        *(ushort4v*)&xb[(size_t)dst * CDIM + h * HDIM + c * 4] = o;
    }
}

// ---------------------------------------------------------------------------
extern "C" void kernel_launch(void* const* d_in, const int* in_sizes, int n_in,
                              void* d_out, int out_size, void* d_ws,
                              size_t ws_size, hipStream_t stream) {
    const float* feats  = (const float*)d_in[0];
    const float* xyz    = (const float*)d_in[1];
    const int*   index1 = (const int*)d_in[4];
    const int*   sortix = (const int*)d_in[5];
    const float* Wq = (const float*)d_in[6];
    const float* bq = (const float*)d_in[7];
    const float* Wk = (const float*)d_in[8];
    const float* bk = (const float*)d_in[9];
    const float* Wv = (const float*)d_in[10];
    const float* bv = (const float*)d_in[11];
    const float* Wp = (const float*)d_in[12];
    const float* bp = (const float*)d_in[13];
    const float* Tq = (const float*)d_in[14];
    const float* Tk = (const float*)d_in[15];
    const float* Tv = (const float*)d_in[16];
    float* out = (float*)d_out;

    char* ws = (char*)d_ws;
    size_t off = 0;
    auto alloc = [&](size_t bytes) -> void* {
        void* p = ws + off;
        off = (off + bytes + 255) & ~(size_t)255;
        return p;
    };
    unsigned short* featsbf = (unsigned short*)alloc((size_t)NPTS * CDIM * 2); // reused as xb
    unsigned short* Wall    = (unsigned short*)alloc((size_t)NXC * CDIM * 2);
    unsigned short* Wpbf    = (unsigned short*)alloc((size_t)CDIM * CDIM * 2);
    float*          Tvh     = (float*)alloc((size_t)NH * THR * HDIM * 4);
    unsigned short* Tqh     = (unsigned short*)alloc((size_t)NH * THR * HDIM * 2);
    unsigned short* Tkh     = (unsigned short*)alloc((size_t)NH * THR * HDIM * 2);
    float*          bfull   = (float*)alloc((size_t)NXC * sizeof(float));
    float*          bproj   = (float*)alloc((size_t)CDIM * sizeof(float));
    unsigned char*  qh8     = (unsigned char*)alloc((size_t)NH * NPTS * 128);
    unsigned char*  kh8     = (unsigned char*)alloc((size_t)NH * NPTS * 128);
    unsigned char*  kvh8    = (unsigned char*)alloc((size_t)NH * NPTS * KVROW);
    unsigned char*  dqh     = (unsigned char*)alloc((size_t)NH * NPTS * THR);
    unsigned char*  dkh     = (unsigned char*)alloc((size_t)NH * NPTS * THR);
    unsigned short* tqk     = (unsigned short*)alloc((size_t)NH * NPTS * KNB * 2);
    unsigned int*   pairs   = (unsigned int*)alloc((size_t)NPTS * KNB * 4);
    int*            xq      = (int*)alloc((size_t)NPTS * 3 * sizeof(int));
    unsigned int*   minbits = (unsigned int*)alloc(16);
    unsigned short* xb      = featsbf; // featsbf dead after gemm0

    // init minbits to 0x7f7f7f7f (~3.4e38) — valid "+inf" stand-in for xyz<=240
    hipMemsetAsync(minbits, 0x7f, 16, stream);
    min_kernel<<<128, 256, 0, stream>>>(xyz, minbits);
    xq_kernel<<<(NPTS + 255) / 256, 256, 0, stream>>>(xyz, sortix, minbits, xq);
    relpack_kernel<<<(NPTS * KNB + 255) / 256, 256, 0, stream>>>(index1, xq, pairs);

    const int prep_total = G0 + G1 + G2 + G3 + G6 + G7 + G4 + G5;
    prep_kernel<<<(prep_total + 255) / 256, 256, 0, stream>>>(
        feats, sortix, Wq, Wk, Wv, Wp, bq, bk, bv, bp, Tv, Tq, Tk,
        featsbf, Wall, Wpbf, Tvh, Tqh, Tkh, bfull, bproj);

    dim3 g0(NXC / 128, NPTS / 128);
    gemm_big<<<g0, 256, 0, stream>>>(featsbf, Wall, bfull, 0, qh8, kh8, kvh8,
                                     (float*)nullptr);

    dim3 gd(NPTS / 128, NH, 2);
    dqdk_kernel<<<gd, 256, 0, stream>>>(qh8, kh8, Tqh, Tkh, dqh, dkh);

    dim3 ga(NPTS / 4, NH);
    tqk_kernel<<<ga, 256, 0, stream>>>(pairs, dqh, dkh, tqk);

    attn_kernel<<<ga, 256, 0, stream>>>(qh8, kvh8, pairs, tqk, Tvh, sortix, xb);

    dim3 g1(CDIM / 128, NPTS / 128);
    gemm_big<<<g1, 256, 0, stream>>>(xb, Wpbf, bproj, 1, (unsigned char*)nullptr,
                                     (unsigned char*)nullptr, (unsigned char*)nullptr,
                                     out);
}

// Round 20
// 203.085 us; speedup vs baseline: 1.0706x; 1.0027x over previous
//
#include <hip/hip_runtime.h>
#include <hip/hip_bf16.h>
#include <cstdint>
#include <cstddef>

#define NPTS 16000
#define KNB  16
#define CDIM 384
#define NH   6
#define HDIM 64
#define T2C  49
#define NL3T 147             // 49*3 table rows
#define THR  160             // per-head table rows padded (147 used)
#define NXC  1152            // q|k|v GEMM output cols
#define KVROW 256            // kvh row: interleaved [c*16]=k[4c..4c+3]|v[4c..4c+3]
// head-major buffers:
//   qh [h][n][128B bf16]   kh [h][n][128B bf16] (contiguous k, for dqdk)
//   kvh[h][n][256B] (k|v interleaved 8B:8B)   dqh/dkh[h][n][160B fp8x8]
//   tqk[h][n][16] bf16     Tvh f32 [h][160][64] (L2-hot)
// featsbf is ORIGINAL order; gemm0 gathers A rows via sortix (per-lane addrs).

static constexpr float WIN    = 6.0f;
static constexpr float QUANT  = 0.24f;
static constexpr float QSCALE = 0.125f; // 64^-0.5
static constexpr float DQS    = 8.0f;   // fp8 range pre-scale for dq/dk
static constexpr float DQSINV = 0.125f;

typedef __attribute__((ext_vector_type(8))) short short8;
typedef __attribute__((ext_vector_type(4))) float floatx4;
typedef __attribute__((ext_vector_type(4))) unsigned short ushort4v;
typedef __attribute__((ext_vector_type(2))) float float2v;

__device__ inline unsigned short f2bf(float x) {
    unsigned int u = __float_as_uint(x);
    unsigned int r = (u + 0x7fffu + ((u >> 16) & 1u)) >> 16;
    return (unsigned short)r;
}
__device__ inline float bf2f(unsigned short b) {
    return __uint_as_float(((unsigned int)b) << 16);
}
__device__ inline float f8tof(unsigned char b) {
    return __builtin_amdgcn_cvt_f32_fp8((int)b, 0);
}
// unpack a bf16x2 word into {elem0, elem1} as f32 (2 VALU ops)
__device__ inline float2v bfpair(unsigned int w) {
    float2v r;
    r.x = __uint_as_float(w << 16);
    r.y = __uint_as_float(w & 0xffff0000u);
    return r;
}

// bijective XCD-chunked (m204) decode for grid (NPTS/4, NH)
__device__ inline void swz_nh(int& nb, int& h) {
    const int gx   = gridDim.x;
    const int nwg  = gx * NH;
    const int orig = blockIdx.y * gx + blockIdx.x;
    const int q    = nwg >> 3, r = nwg & 7;
    const int xcd  = orig & 7, idx = orig >> 3;
    const int wg   = (xcd < r ? xcd * (q + 1) : r * (q + 1) + (xcd - r) * q) + idx;
    h  = wg / gx;
    nb = wg % gx;
}

// ---------------------------------------------------------------- min reduce
// minbits pre-set to 0x7f7f7f7f (≈3.4e38) via hipMemsetAsync
__global__ void min_kernel(const float* __restrict__ xyz,
                           unsigned int* __restrict__ minbits) {
    float m0 = INFINITY, m1 = INFINITY, m2 = INFINITY;
    for (int i = blockIdx.x * blockDim.x + threadIdx.x; i < NPTS;
         i += gridDim.x * blockDim.x) {
        m0 = fminf(m0, xyz[i * 3 + 0]);
        m1 = fminf(m1, xyz[i * 3 + 1]);
        m2 = fminf(m2, xyz[i * 3 + 2]);
    }
#pragma unroll
    for (int off = 1; off < 64; off <<= 1) {
        m0 = fminf(m0, __shfl_xor(m0, off, 64));
        m1 = fminf(m1, __shfl_xor(m1, off, 64));
        m2 = fminf(m2, __shfl_xor(m2, off, 64));
    }
    if ((threadIdx.x & 63) == 0) {
        atomicMin(&minbits[0], __float_as_uint(m0)); // xyz >= 0
        atomicMin(&minbits[1], __float_as_uint(m1));
        atomicMin(&minbits[2], __float_as_uint(m2));
    }
}

// ------------------------------------------------------------- quantize xyz
__global__ void xq_kernel(const float* __restrict__ xyz,
                          const int* __restrict__ sort_idx,
                          const unsigned int* __restrict__ minbits,
                          int* __restrict__ xq) {
    int n = blockIdx.x * blockDim.x + threadIdx.x;
    if (n >= NPTS) return;
    int orig = sort_idx[n];
#pragma unroll
    for (int t = 0; t < 3; ++t) {
        float mn = __uint_as_float(minbits[t]);
        float v  = xyz[orig * 3 + t] - mn;   // >= 0
        float md = fmodf(v, WIN);            // == np.mod for non-negative
        float q  = floorf(md / QUANT);
        xq[n * 3 + t] = (int)q;
    }
}

// ----------------------------------------------- pack (key, rel0..2) per pair
__global__ void relpack_kernel(const int* __restrict__ idx1,
                               const int* __restrict__ xq,
                               unsigned int* __restrict__ pairs) {
    int m = blockIdx.x * blockDim.x + threadIdx.x;
    if (m >= NPTS * KNB) return;
    int n = m >> 4;
    int key = idx1[m];
    int r0 = xq[n * 3 + 0] - xq[key * 3 + 0] + 24; r0 = min(max(r0, 0), T2C - 1);
    int r1 = xq[n * 3 + 1] - xq[key * 3 + 1] + 24; r1 = min(max(r1, 0), T2C - 1);
    int r2 = xq[n * 3 + 2] - xq[key * 3 + 2] + 24; r2 = min(max(r2, 0), T2C - 1);
    pairs[m] = (unsigned)key | ((unsigned)r0 << 14) | ((unsigned)r1 << 20) |
               ((unsigned)r2 << 26);
}

// ------------------------ fused prep: feats convert (coalesced), weight packs
// Per-head reordered tables: Th[h][jr][d] = T[(jr*6 + h)*64 + d], jr=l*3+t<147
#define G0 (NPTS * CDIM / 4)       // featsbf float4 groups (NO gather)
#define G1 (3 * CDIM * CDIM)       // Wall (q|k|v weight rows)
#define G2 (CDIM * CDIM)           // Wpbf
#define G3 (NH * THR * HDIM)       // Tvh (per-head reordered, f32)
#define G6 (NH * THR * HDIM)       // Tqh (bf16)
#define G7 (NH * THR * HDIM)       // Tkh (bf16)
#define G4 (3 * CDIM)              // bfull
#define G5 (CDIM)                  // bproj
__global__ void prep_kernel(const float* __restrict__ feats,
                            const float* __restrict__ Wq,
                            const float* __restrict__ Wk,
                            const float* __restrict__ Wv,
                            const float* __restrict__ Wp,
                            const float* __restrict__ bq,
                            const float* __restrict__ bk,
                            const float* __restrict__ bv,
                            const float* __restrict__ bp,
                            const float* __restrict__ Tv,
                            const float* __restrict__ Tq,
                            const float* __restrict__ Tk,
                            unsigned short* __restrict__ featsbf,
                            unsigned short* __restrict__ Wall,
                            unsigned short* __restrict__ Wpbf,
                            float* __restrict__ Tvh,
                            unsigned short* __restrict__ Tqh,
                            unsigned short* __restrict__ Tkh,
                            float* __restrict__ bfull,
                            float* __restrict__ bproj) {
    int i = blockIdx.x * blockDim.x + threadIdx.x;
    if (i < G0) {
        const float4 v = *(const float4*)&feats[(size_t)i * 4];
        ushort4v o;
        o.x = f2bf(v.x); o.y = f2bf(v.y); o.z = f2bf(v.z); o.w = f2bf(v.w);
        *(ushort4v*)&featsbf[(size_t)i * 4] = o;
        return;
    }
    i -= G0;
    if (i < G1) {
        int j = i / CDIM, k = i % CDIM;
        float v = (j < 384) ? Wq[j * CDIM + k]
                : (j < 768) ? Wk[(j - 384) * CDIM + k]
                            : Wv[(j - 768) * CDIM + k];
        Wall[i] = f2bf(v);
        return;
    }
    i -= G1;
    if (i < G2) { Wpbf[i] = f2bf(Wp[i]); return; }
    i -= G2;
    if (i < G3) {
        int jr = (i / HDIM) % THR, d = i % HDIM, h = i / (THR * HDIM);
        Tvh[i] = (jr < NL3T) ? Tv[(size_t)(jr * 6 + h) * HDIM + d] : 0.0f;
        return;
    }
    i -= G3;
    if (i < G6) {
        int jr = (i / HDIM) % THR, d = i % HDIM, h = i / (THR * HDIM);
        Tqh[i] = (jr < NL3T) ? f2bf(Tq[(size_t)(jr * 6 + h) * HDIM + d])
                             : (unsigned short)0;
        return;
    }
    i -= G6;
    if (i < G7) {
        int jr = (i / HDIM) % THR, d = i % HDIM, h = i / (THR * HDIM);
        Tkh[i] = (jr < NL3T) ? f2bf(Tk[(size_t)(jr * 6 + h) * HDIM + d])
                             : (unsigned short)0;
        return;
    }
    i -= G7;
    if (i < G4) {
        bfull[i] = (i < 384) ? bq[i] : (i < 768) ? bk[i - 384] : bv[i - 768];
        return;
    }
    i -= G4;
    if (i < G5) { bproj[i] = bp[i]; }
}

// ------------------------------------------------------ fused bf16 MFMA GEMM
// 128x128 tile, 256 threads (4 waves), bijective XCD-swizzled grid.
// mode 0: A=featsbf GATHERED via gidx, W=Wall [1152x384] -> qh/kh/kvh head-major
// mode 1: A=xb (no gather), W=Wpbf [384x384] -> out f32
__global__ __launch_bounds__(256) void gemm_big(
    const unsigned short* __restrict__ Abf,
    const unsigned short* __restrict__ Wmat,
    const float* __restrict__ bias,
    const int* __restrict__ gidx,     // null => identity
    int mode,
    unsigned char* __restrict__ qh8, unsigned char* __restrict__ kh8,
    unsigned char* __restrict__ kvh8, float* __restrict__ outf) {
    __shared__ unsigned short As[128 * 64];
    __shared__ unsigned short Bs[128 * 64];
    const int tid  = threadIdx.x;
    const int lane = tid & 63;
    const int w    = tid >> 6;
    const int wm   = w >> 1, wn = w & 1;

    // bijective XCD-aware swizzle (m204)
    const int nwg  = gridDim.x * gridDim.y;
    const int orig = blockIdx.y * gridDim.x + blockIdx.x;
    const int qq   = nwg >> 3, rr = nwg & 7;
    const int xcd  = orig & 7, idx = orig >> 3;
    const int wg   = (xcd < rr ? xcd * (qq + 1) : rr * (qq + 1) + (xcd - rr) * qq) + idx;
    const int jn0  = (wg % gridDim.x) * 128;   // column tile (fast-moving)
    const int m0   = (wg / gridDim.x) * 128;   // row tile

    floatx4 acc[4][4];
#pragma unroll
    for (int i = 0; i < 4; ++i)
#pragma unroll
        for (int j = 0; j < 4; ++j) acc[i][j] = (floatx4)0.0f;

    // per-thread A-row (8 rows per segment; this lane always loads the same row)
    const int arow_s = (lane >> 3);           // row within segment
    for (int kt = 0; kt < 6; ++kt) {
        const int k0 = kt * 64;
        const int col = (lane & 7) * 8;
#pragma unroll
        for (int q = 0; q < 4; ++q) {
            const int s    = w * 4 + q;            // 1KB segment id
            const int row  = s * 8 + arow_s;
            const int ar   = gidx ? gidx[m0 + row] : (m0 + row);
            const unsigned short* ga = Abf  + (size_t)ar * CDIM + k0 + col;
            const unsigned short* gb = Wmat + (size_t)(jn0 + row) * CDIM + k0 + col;
            __builtin_amdgcn_global_load_lds(
                (const __attribute__((address_space(1))) void*)ga,
                (__attribute__((address_space(3))) void*)&As[s * 512], 16, 0, 0);
            __builtin_amdgcn_global_load_lds(
                (const __attribute__((address_space(1))) void*)gb,
                (__attribute__((address_space(3))) void*)&Bs[s * 512], 16, 0, 0);
        }
        __syncthreads();
#pragma unroll
        for (int ks = 0; ks < 2; ++ks) {
            short8 a[4], b[4];
#pragma unroll
            for (int mi = 0; mi < 4; ++mi) {
                int row = wm * 64 + mi * 16 + (lane & 15);
                a[mi] = *(const short8*)&As[row * 64 + ks * 32 + (lane >> 4) * 8];
            }
#pragma unroll
            for (int ni = 0; ni < 4; ++ni) {
                int jr = wn * 64 + ni * 16 + (lane & 15);
                b[ni] = *(const short8*)&Bs[jr * 64 + ks * 32 + (lane >> 4) * 8];
            }
            // swapped operands: acc frag = 4 consecutive output cols of one row
#pragma unroll
            for (int mi = 0; mi < 4; ++mi)
#pragma unroll
                for (int ni = 0; ni < 4; ++ni)
                    acc[mi][ni] = __builtin_amdgcn_mfma_f32_16x16x32_bf16(
                        b[ni], a[mi], acc[mi][ni], 0, 0, 0);
        }
        __syncthreads();
    }

#pragma unroll
    for (int mi = 0; mi < 4; ++mi) {
        const int n = m0 + wm * 64 + mi * 16 + (lane & 15);
#pragma unroll
        for (int ni = 0; ni < 4; ++ni) {
            const int jjb = jn0 + wn * 64 + ni * 16 + (lane >> 4) * 4;
            const float4 b4 = *(const float4*)&bias[jjb];
            const float v0 = acc[mi][ni][0] + b4.x;
            const float v1 = acc[mi][ni][1] + b4.y;
            const float v2 = acc[mi][ni][2] + b4.z;
            const float v3 = acc[mi][ni][3] + b4.w;
            if (mode == 0) {
                if (jjb < 384) {                    // q -> qh (x QSCALE)
                    const int h = jjb >> 6, d = jjb & 63;
                    ushort4v o;
                    o.x = f2bf(v0 * QSCALE); o.y = f2bf(v1 * QSCALE);
                    o.z = f2bf(v2 * QSCALE); o.w = f2bf(v3 * QSCALE);
                    *(ushort4v*)(qh8 + ((size_t)h * NPTS + n) * 128 + d * 2) = o;
                } else if (jjb < 768) {             // k -> kh (contig) + kvh
                    const int jj = jjb - 384;
                    const int h = jj >> 6, d = jj & 63;
                    ushort4v o;
                    o.x = f2bf(v0); o.y = f2bf(v1);
                    o.z = f2bf(v2); o.w = f2bf(v3);
                    *(ushort4v*)(kh8 + ((size_t)h * NPTS + n) * 128 + d * 2) = o;
                    *(ushort4v*)(kvh8 + ((size_t)h * NPTS + n) * KVROW + d * 4) = o;
                } else {                            // v -> kvh interleaved
                    const int jj = jjb - 768;
                    const int h = jj >> 6, d = jj & 63;
                    ushort4v o;
                    o.x = f2bf(v0); o.y = f2bf(v1);
                    o.z = f2bf(v2); o.w = f2bf(v3);
                    *(ushort4v*)(kvh8 + ((size_t)h * NPTS + n) * KVROW + d * 4 + 8) = o;
                }
            } else {
                float4 o; o.x = v0; o.y = v1; o.z = v2; o.w = v3;
                *(float4*)&outf[(size_t)n * CDIM + jjb] = o;
            }
        }
    }
}

// --------------------------- per-head dq/dk low-rank GEMM (K=64, MFMA)
// grid (NPTS/128, NH, 2).  dq[h][n][jr] = DQS * q[n,h,:].Th[h][jr,:]
__global__ __launch_bounds__(256) void dqdk_kernel(
    const unsigned char* __restrict__ qh8,
    const unsigned char* __restrict__ kh8,
    const unsigned short* __restrict__ Tqh,
    const unsigned short* __restrict__ Tkh,
    unsigned char* __restrict__ dqh,
    unsigned char* __restrict__ dkh) {
    __shared__ unsigned short As[128 * 64];   // q/k head-slices (n-tile)
    __shared__ unsigned short Bs[THR * 64];   // Th rows (jr 0..159)
    const int tid  = threadIdx.x;
    const int lane = tid & 63;
    const int w    = tid >> 6;
    const int wm   = w >> 1, wn = w & 1;
    const int h    = blockIdx.y;
    const bool isk = blockIdx.z != 0;
    const unsigned char* srcb = (isk ? kh8 : qh8) + (size_t)h * NPTS * 128;
    unsigned char* dst = (isk ? dkh : dqh) + (size_t)h * NPTS * THR;
    const unsigned short* T = (isk ? Tkh : Tqh) + (size_t)h * THR * HDIM;
    const int m0 = blockIdx.x * 128;

#pragma unroll
    for (int q = 0; q < 4; ++q) {          // A: 16 x 1KB segments
        const int s   = w * 4 + q;
        const int row = s * 8 + (lane >> 3);
        const unsigned char* ga = srcb + (size_t)(m0 + row) * 128 + (lane & 7) * 16;
        __builtin_amdgcn_global_load_lds(
            (const __attribute__((address_space(1))) void*)ga,
            (__attribute__((address_space(3))) void*)&As[s * 512], 16, 0, 0);
    }
#pragma unroll
    for (int q = 0; q < 5; ++q) {          // B: 20 x 1KB segments (160 rows)
        const int s   = w * 5 + q;
        const int row = s * 8 + (lane >> 3);
        const unsigned short* gb = T + (size_t)row * HDIM + (lane & 7) * 8;
        __builtin_amdgcn_global_load_lds(
            (const __attribute__((address_space(1))) void*)gb,
            (__attribute__((address_space(3))) void*)&Bs[s * 512], 16, 0, 0);
    }
    __syncthreads();

    floatx4 acc[4][5];
#pragma unroll
    for (int i = 0; i < 4; ++i)
#pragma unroll
        for (int j = 0; j < 5; ++j) acc[i][j] = (floatx4)0.0f;

#pragma unroll
    for (int ks = 0; ks < 2; ++ks) {
        short8 a[4], b[5];
#pragma unroll
        for (int mi = 0; mi < 4; ++mi) {
            int row = wm * 64 + mi * 16 + (lane & 15);
            a[mi] = *(const short8*)&As[row * 64 + ks * 32 + (lane >> 4) * 8];
        }
#pragma unroll
        for (int ni = 0; ni < 5; ++ni) {
            int jr = wn * 80 + ni * 16 + (lane & 15);
            b[ni] = *(const short8*)&Bs[jr * 64 + ks * 32 + (lane >> 4) * 8];
        }
#pragma unroll
        for (int mi = 0; mi < 4; ++mi)
#pragma unroll
            for (int ni = 0; ni < 5; ++ni)
                acc[mi][ni] = __builtin_amdgcn_mfma_f32_16x16x32_bf16(
                    b[ni], a[mi], acc[mi][ni], 0, 0, 0);
    }

#pragma unroll
    for (int mi = 0; mi < 4; ++mi) {
        const int n = m0 + wm * 64 + mi * 16 + (lane & 15);
#pragma unroll
        for (int ni = 0; ni < 5; ++ni) {
            const int jr0 = wn * 80 + ni * 16 + (lane >> 4) * 4;
            int u = __builtin_amdgcn_cvt_pk_fp8_f32(acc[mi][ni][0] * DQS,
                                                    acc[mi][ni][1] * DQS, 0, false);
            u = __builtin_amdgcn_cvt_pk_fp8_f32(acc[mi][ni][2] * DQS,
                                                acc[mi][ni][3] * DQS, u, true);
            *(unsigned int*)(dst + (size_t)n * THR + jr0) = (unsigned)u;
        }
    }
}

// ----------------------------- tqk pre-pass: per (query, head, pair) table sum
// grid (NPTS/4, NH) swizzled; block 256 = 4 waves (wave = query).
// lane: p = lane>>2 (pair), s = lane&3 (t axis; s==3 idle).
__global__ __launch_bounds__(256) void tqk_kernel(
    const unsigned int* __restrict__ pairs,
    const unsigned char* __restrict__ dqh,
    const unsigned char* __restrict__ dkh,
    unsigned short* __restrict__ tqk) {
    int nb, h;
    swz_nh(nb, h);
    const int n = nb * 4 + (threadIdx.x >> 6);
    const int lane = threadIdx.x & 63;
    const int p = lane >> 2, s = lane & 3;

    const unsigned int pv = pairs[n * KNB + p];
    float v = 0.0f;
    if (s < 3) {
        const int key = (int)(pv & 0x3FFFu);
        const int r = (int)((pv >> (14 + 6 * s)) & 63u);
        const int jr = r * 3 + s;
        v = f8tof(dqh[(size_t)h * NPTS * THR + (size_t)n * THR + jr]) +
            f8tof(dkh[(size_t)h * NPTS * THR + (size_t)key * THR + jr]);
    }
    v += __shfl_xor(v, 1, 64);
    v += __shfl_xor(v, 2, 64);
    if (s == 0)
        tqk[((size_t)h * NPTS + n) * KNB + p] = f2bf(v * DQSINV);
}

// -------------------------------------------------- attention main pass
// grid (NPTS/4, NH) swizzled; block 256 = 4 waves; wave = (query, head).
// lane = pp*16 + c. ONE 16B load per pair fetches k+v (interleaved row);
// Tv f32 (L2-hot); tqr precomputed (tqk pass).
__global__ __launch_bounds__(256) void attn_kernel(
    const unsigned char* __restrict__ qh8,
    const unsigned char* __restrict__ kvh8,
    const unsigned int* __restrict__ pairs,
    const unsigned short* __restrict__ tqk,
    const float* __restrict__ Tvh,
    const int* __restrict__ sortix,
    unsigned short* __restrict__ xb) {
    int nb, h;
    swz_nh(nb, h);
    const int n = nb * 4 + (threadIdx.x >> 6);
    const int lane = threadIdx.x & 63;
    const int pp = lane >> 4, c = lane & 15;

    const unsigned char* kvb = kvh8 + (size_t)h * NPTS * KVROW;        // uniform
    const float* Tvb = Tvh + (size_t)h * THR * HDIM;                   // uniform
    const unsigned short* tqr = tqk + ((size_t)h * NPTS + n) * KNB;

    const uint2 qw = *(const uint2*)(qh8 + ((size_t)h * NPTS + n) * 128 + c * 8);
    const float2v q01 = bfpair(qw.x), q23 = bfpair(qw.y);

    unsigned int pv[4];
#pragma unroll
    for (int g = 0; g < 4; ++g) pv[g] = pairs[n * KNB + g * 4 + pp];

    int t0o[4], t1o[4], t2o[4];
    uint2 vw[4];
    float lg[4];
#pragma unroll
    for (int g = 0; g < 4; ++g) {
        t0o[g] = (int)((pv[g] >> 14) & 63u) * 192 + c * 4;        // f32 idx, t=0
        t1o[g] = (int)((pv[g] >> 20) & 63u) * 192 + 64 + c * 4;   // t=1
        t2o[g] = (int)(pv[g] >> 26) * 192 + 128 + c * 4;          // t=2
        const uint4 kv4 =
            *(const uint4*)(kvb + (int)(pv[g] & 0x3FFFu) * KVROW + c * 16);
        float2v d = q01 * bfpair(kv4.x) + q23 * bfpair(kv4.y);
        lg[g] = d.x + d.y;
        vw[g].x = kv4.z; vw[g].y = kv4.w;   // v half, used after softmax
    }
#pragma unroll
    for (int m = 1; m <= 8; m <<= 1)
#pragma unroll
        for (int g = 0; g < 4; ++g) lg[g] += __shfl_xor(lg[g], m, 64);
#pragma unroll
    for (int g = 0; g < 4; ++g) lg[g] += bf2f(tqr[g * 4 + pp]);

    // softmax over 16 pairs (4 in-lane x 4 pp-groups)
    float mx = fmaxf(fmaxf(lg[0], lg[1]), fmaxf(lg[2], lg[3]));
    mx = fmaxf(mx, __shfl_xor(mx, 16, 64));
    mx = fmaxf(mx, __shfl_xor(mx, 32, 64));
    float e[4], s = 0.f;
#pragma unroll
    for (int g = 0; g < 4; ++g) { e[g] = __expf(lg[g] - mx); s += e[g]; }
    s += __shfl_xor(s, 16, 64);
    s += __shfl_xor(s, 32, 64);
    const float inv = __builtin_amdgcn_rcpf(s);

    floatx4 xa = (floatx4)0.0f;
#pragma unroll
    for (int g = 0; g < 4; ++g) {
        const float wgt = e[g] * inv;
        const float2v v01 = bfpair(vw[g].x), v23 = bfpair(vw[g].y);
        floatx4 vv;
        vv[0] = v01.x; vv[1] = v01.y; vv[2] = v23.x; vv[3] = v23.y;
        const floatx4 a0 = *(const floatx4*)&Tvb[t0o[g]];
        const floatx4 a1 = *(const floatx4*)&Tvb[t1o[g]];
        const floatx4 a2 = *(const floatx4*)&Tvb[t2o[g]];
        xa += wgt * (vv + a0 + a1 + a2);
    }
    float xa0 = xa[0], xa1 = xa[1], xa2 = xa[2], xa3 = xa[3];
#pragma unroll
    for (int m = 16; m <= 32; m <<= 1) {
        xa0 += __shfl_xor(xa0, m, 64);
        xa1 += __shfl_xor(xa1, m, 64);
        xa2 += __shfl_xor(xa2, m, 64);
        xa3 += __shfl_xor(xa3, m, 64);
    }
    if (pp == 0) {
        const int dst = sortix[n]; // unsort
        ushort4v o;
        o.x = f2bf(xa0); o.y = f2bf(xa1); o.z = f2bf(xa2); o.w = f2bf(xa3);
        *(ushort4v*)&xb[(size_t)dst * CDIM + h * HDIM + c * 4] = o;
    }
}

// ---------------------------------------------------------------------------
extern "C" void kernel_launch(void* const* d_in, const int* in_sizes, int n_in,
                              void* d_out, int out_size, void* d_ws,
                              size_t ws_size, hipStream_t stream) {
    const float* feats  = (const float*)d_in[0];
    const float* xyz    = (const float*)d_in[1];
    const int*   index1 = (const int*)d_in[4];
    const int*   sortix = (const int*)d_in[5];
    const float* Wq = (const float*)d_in[6];
    const float* bq = (const float*)d_in[7];
    const float* Wk = (const float*)d_in[8];
    const float* bk = (const float*)d_in[9];
    const float* Wv = (const float*)d_in[10];
    const float* bv = (const float*)d_in[11];
    const float* Wp = (const float*)d_in[12];
    const float* bp = (const float*)d_in[13];
    const float* Tq = (const float*)d_in[14];
    const float* Tk = (const float*)d_in[15];
    const float* Tv = (const float*)d_in[16];
    float* out = (float*)d_out;

    char* ws = (char*)d_ws;
    size_t off = 0;
    auto alloc = [&](size_t bytes) -> void* {
        void* p = ws + off;
        off = (off + bytes + 255) & ~(size_t)255;
        return p;
    };
    unsigned short* featsbf = (unsigned short*)alloc((size_t)NPTS * CDIM * 2); // reused as xb
    unsigned short* Wall    = (unsigned short*)alloc((size_t)NXC * CDIM * 2);
    unsigned short* Wpbf    = (unsigned short*)alloc((size_t)CDIM * CDIM * 2);
    float*          Tvh     = (float*)alloc((size_t)NH * THR * HDIM * 4);
    unsigned short* Tqh     = (unsigned short*)alloc((size_t)NH * THR * HDIM * 2);
    unsigned short* Tkh     = (unsigned short*)alloc((size_t)NH * THR * HDIM * 2);
    float*          bfull   = (float*)alloc((size_t)NXC * sizeof(float));
    float*          bproj   = (float*)alloc((size_t)CDIM * sizeof(float));
    unsigned char*  qh8     = (unsigned char*)alloc((size_t)NH * NPTS * 128);
    unsigned char*  kh8     = (unsigned char*)alloc((size_t)NH * NPTS * 128);
    unsigned char*  kvh8    = (unsigned char*)alloc((size_t)NH * NPTS * KVROW);
    unsigned char*  dqh     = (unsigned char*)alloc((size_t)NH * NPTS * THR);
    unsigned char*  dkh     = (unsigned char*)alloc((size_t)NH * NPTS * THR);
    unsigned short* tqk     = (unsigned short*)alloc((size_t)NH * NPTS * KNB * 2);
    unsigned int*   pairs   = (unsigned int*)alloc((size_t)NPTS * KNB * 4);
    int*            xq      = (int*)alloc((size_t)NPTS * 3 * sizeof(int));
    unsigned int*   minbits = (unsigned int*)alloc(16);
    unsigned short* xb      = featsbf; // featsbf dead after gemm0

    // init minbits to 0x7f7f7f7f (~3.4e38) — valid "+inf" stand-in for xyz<=240
    hipMemsetAsync(minbits, 0x7f, 16, stream);
    min_kernel<<<128, 256, 0, stream>>>(xyz, minbits);
    xq_kernel<<<(NPTS + 255) / 256, 256, 0, stream>>>(xyz, sortix, minbits, xq);
    relpack_kernel<<<(NPTS * KNB + 255) / 256, 256, 0, stream>>>(index1, xq, pairs);

    const int prep_total = G0 + G1 + G2 + G3 + G6 + G7 + G4 + G5;
    prep_kernel<<<(prep_total + 255) / 256, 256, 0, stream>>>(
        feats, Wq, Wk, Wv, Wp, bq, bk, bv, bp, Tv, Tq, Tk,
        featsbf, Wall, Wpbf, Tvh, Tqh, Tkh, bfull, bproj);

    dim3 g0(NXC / 128, NPTS / 128);
    gemm_big<<<g0, 256, 0, stream>>>(featsbf, Wall, bfull, sortix, 0,
                                     qh8, kh8, kvh8, (float*)nullptr);

    dim3 gd(NPTS / 128, NH, 2);
    dqdk_kernel<<<gd, 256, 0, stream>>>(qh8, kh8, Tqh, Tkh, dqh, dkh);

    dim3 ga(NPTS / 4, NH);
    tqk_kernel<<<ga, 256, 0, stream>>>(pairs, dqh, dkh, tqk);

    attn_kernel<<<ga, 256, 0, stream>>>(qh8, kvh8, pairs, tqk, Tvh, sortix, xb);

    dim3 g1(CDIM / 128, NPTS / 128);
    gemm_big<<<g1, 256, 0, stream>>>(xb, Wpbf, bproj, (const int*)nullptr, 1,
                                     (unsigned char*)nullptr,
                                     (unsigned char*)nullptr,
                                     (unsigned char*)nullptr, out);
}